// Round 6
// baseline (2272.413 us; speedup 1.0000x reference)
//
#include <hip/hip_runtime.h>
#include <hip/hip_bf16.h>

// ---------------------------------------------------------------------------
// LSTM-CRF forward on MI355X.
// R6: slice-parallel LSTM with single-barrier steps:
//  - waves 0-1 compute ALL 4 gates for 16 batches each -> C-owner == state
//    owner, no GT exchange.
//  - A fragments loaded direct-to-register (coalesced dwordx4 from LLC).
//  - producer h: shfl-pack -> 1KB LDS stage -> 4 waves store one contiguous
//    256B run each (fast vmcnt drain) -> per-wave s_waitcnt -> per-wave flag.
//  - sync protocol (proven R4/R5): write-through relaxed atomic stores,
//    waitcnt drain, relaxed flag; consumer relaxed poll + normal loads of
//    once-per-dispatch shuffled slots.
// GEMMs: 64x64-per-wave MFMA tiles, z-merged launches.
// ---------------------------------------------------------------------------

#define Bv 32
#define Tv 256
#define Ev 300
#define HDv 256
#define Kv 64
#define MROWS (Bv * Tv)          // 8192
#define K0PAD 320                // 301 padded to mult of 32
#define GATES 1024               // 4*HD
#define NSLICE 16                // j-slices per dir
#define JS 16                    // j per slice
#define WFRAG_PER_DS (4 * 8 * 64 * 8)   // shorts per (dir,slice) weight block

typedef __bf16 v8bf __attribute__((ext_vector_type(8)));
typedef float  v4f  __attribute__((ext_vector_type(4)));

__device__ __forceinline__ unsigned short f2bf(float f) {
    unsigned u = __float_as_uint(f);
    unsigned r = (u + 0x7fffu + ((u >> 16) & 1u)) >> 16;
    return (unsigned short)r;
}
__device__ __forceinline__ float sigf(float x) { return 1.0f / (1.0f + __expf(-x)); }
__device__ __forceinline__ float tanhf2(float x) {
    x = fminf(15.f, fmaxf(-15.f, x));
    float e = __expf(2.f * x);
    return (e - 1.f) / (e + 1.f);
}

// ---------------- prep kernels ----------------

__global__ void conv_weights(const float* w0f, const float* w0b,
                             const float* w1f, const float* w1b,
                             const float* outw,
                             unsigned short* dW0, unsigned short* dW1,
                             unsigned short* dOW) {
    int z = blockIdx.z;
    const float* src; unsigned short* dst; int rows, kin, kout;
    if (z == 0)      { src = w0f;  dst = dW0;                rows = 1024; kin = 301; kout = K0PAD; }
    else if (z == 1) { src = w0b;  dst = dW0 + 1024 * K0PAD; rows = 1024; kin = 301; kout = K0PAD; }
    else if (z == 2) { src = w1f;  dst = dW1;                rows = 1024; kin = 512; kout = 512; }
    else if (z == 3) { src = w1b;  dst = dW1 + 1024 * 512;   rows = 1024; kin = 512; kout = 512; }
    else             { src = outw; dst = dOW;                rows = 64;   kin = 512; kout = 512; }
    int idx = blockIdx.x * 256 + threadIdx.x;
    if (idx >= rows * kout) return;
    int j = idx / kout, k = idx - j * kout;
    dst[idx] = (k < kin) ? f2bf(src[j * kin + k]) : (unsigned short)0;
}

// Whh [1024,256] fp32 -> bf16 MFMA B-fragment order:
// per (layer*2+dir) z: [slice(16)][gate(4)][kt(8)][lane(64)][e(8)]
// value = Whh[gate*256 + slice*16 + (lane&15)][kt*32 + (lane>>4)*8 + e]
__global__ void whh_frag(const float* h0f, const float* h0b,
                         const float* h1f, const float* h1b, unsigned short* Wfrag) {
    int z = blockIdx.z;
    const float* src = (z == 0) ? h0f : (z == 1) ? h0b : (z == 2) ? h1f : h1b;
    unsigned short* dst = Wfrag + (size_t)z * (NSLICE * WFRAG_PER_DS);
    int idx = blockIdx.x * 256 + threadIdx.x;          // 0..262143
    int e = idx & 7, ln = (idx >> 3) & 63, kt = (idx >> 9) & 7;
    int g = (idx >> 12) & 3, sl = idx >> 14;
    int n = g * 256 + sl * JS + (ln & 15);
    int k = kt * 32 + (ln >> 4) * 8 + e;
    dst[idx] = f2bf(src[n * 256 + k]);
}

__global__ void bias_sum(const float* a0, const float* b0, const float* a1, const float* b1,
                         const float* a2, const float* b2, const float* a3, const float* b3,
                         float* bias) {
    int idx = blockIdx.x * 256 + threadIdx.x;      // 0..4095
    int dl = idx >> 10, j = idx & 1023;
    const float* A = (dl == 0) ? a0 : (dl == 1) ? a1 : (dl == 2) ? a2 : a3;
    const float* B = (dl == 0) ? b0 : (dl == 1) ? b1 : (dl == 2) ? b2 : b3;
    bias[idx] = A[j] + B[j];
}

__global__ void calc_len(const int* x, int* lengths) {
    __shared__ int cnt;
    if (threadIdx.x == 0) cnt = 0;
    __syncthreads();
    if (x[blockIdx.x * Tv + threadIdx.x] > 0) atomicAdd(&cnt, 1);
    __syncthreads();
    if (threadIdx.x == 0) lengths[blockIdx.x] = cnt;
}

__global__ void zero_flags(int* flags) {
    flags[blockIdx.x * 256 + threadIdx.x] = 0;
}

// X0 row = [embed[tok](300) | f(1) | zeros(19)] as bf16
__global__ void embed_pack(const int* __restrict__ x, const float* __restrict__ f,
                           const float* __restrict__ embed, unsigned short* __restrict__ X0) {
    int row = blockIdx.x;
    int tok = x[row];
    float fv = f[row];
    const float* e = embed + (size_t)tok * Ev;
    for (int k = threadIdx.x; k < K0PAD; k += 64) {
        float v = (k < Ev) ? e[k] : ((k == Ev) ? fv : 0.f);
        X0[(size_t)row * K0PAD + k] = f2bf(v);
    }
}

// ------- MFMA GEMM 64x64 per wave: C[M,N] = X[M,K] @ W[N,K]^T + bias[N] ----
__global__ __launch_bounds__(64) void mfma_gemm64(
    const unsigned short* __restrict__ X, int ldx,
    const unsigned short* __restrict__ Wt, int ldw, int wstride_z,
    const float* __restrict__ bias, int bstride_z,
    float* __restrict__ C, int ldc, size_t cstride_z, int K) {
    const int lane = threadIdx.x;
    const int z = blockIdx.z;
    const unsigned short* W = Wt + (size_t)z * wstride_z;
    const float* bz = bias + (size_t)z * bstride_z;
    float* Cz = C + (size_t)z * cstride_z;
    const int m0 = blockIdx.x * 64, n0 = blockIdx.y * 64;
    const int r = lane & 15, q = lane >> 4;
    const unsigned short* xp[4];
    const unsigned short* wp[4];
#pragma unroll
    for (int i = 0; i < 4; ++i) {
        xp[i] = X + (size_t)(m0 + 16 * i + r) * ldx + q * 8;
        wp[i] = W + (size_t)(n0 + 16 * i + r) * ldw + q * 8;
    }
    v4f acc[4][4];
#pragma unroll
    for (int i = 0; i < 4; ++i)
#pragma unroll
        for (int j = 0; j < 4; ++j) acc[i][j] = (v4f){0.f, 0.f, 0.f, 0.f};
#pragma unroll 2
    for (int k = 0; k < K; k += 32) {
        v8bf a[4], b[4];
#pragma unroll
        for (int i = 0; i < 4; ++i) { a[i] = *(const v8bf*)(xp[i] + k); b[i] = *(const v8bf*)(wp[i] + k); }
#pragma unroll
        for (int i = 0; i < 4; ++i)
#pragma unroll
            for (int j = 0; j < 4; ++j)
                acc[i][j] = __builtin_amdgcn_mfma_f32_16x16x32_bf16(a[i], b[j], acc[i][j], 0, 0, 0);
    }
#pragma unroll
    for (int j = 0; j < 4; ++j) {
        int col = n0 + 16 * j + r;
        float bv = bz[col];
#pragma unroll
        for (int i = 0; i < 4; ++i)
#pragma unroll
            for (int e = 0; e < 4; ++e)
                Cz[(size_t)(m0 + 16 * i + q * 4 + e) * ldc + col] = acc[i][j][e] + bv;
    }
}

// ---------------- slice-parallel LSTM (R6) ----------------
// Hstate slot (4096 dwords) = MFMA A-fragment order:
//   dword(b,pc) = (b&16)*128 + ((pc>>4)*64 + ((pc>>2)&3)*16 + (b&15))*4 + (pc&3)
// b=batch, pc=j-pair column 0..127. flags: [dir][step][64] (slice*4+wave).
__global__ __launch_bounds__(256) void lstm_slice(
    const float* __restrict__ Gin,
    const unsigned short* __restrict__ Wfrag,
    unsigned int* __restrict__ Hstate,
    unsigned int* __restrict__ Hout,
    int* __restrict__ flags,
    const int* __restrict__ lengths) {
    const int d = blockIdx.y, sl = blockIdx.x;
    const int tid = threadIdx.x;
    const int lane = tid & 63, wv = tid >> 6;
    const bool comp = (wv < 2);
    const int ar = lane & 15, aq = lane >> 4;

    __shared__ __align__(16) unsigned int stg[256];

    // compute waves: B-fragments for all 4 gates in registers (128 VGPRs)
    v8bf wreg[4][8];
    int lenr[4];
    float cst[4] = {0.f, 0.f, 0.f, 0.f}, hst[4] = {0.f, 0.f, 0.f, 0.f};
    if (comp) {
        const unsigned short* wb = Wfrag + (size_t)(d * NSLICE + sl) * WFRAG_PER_DS;
#pragma unroll
        for (int g = 0; g < 4; ++g)
#pragma unroll
            for (int kt = 0; kt < 8; ++kt)
                wreg[g][kt] = *(const v8bf*)(wb + ((size_t)(g * 8 + kt) * 64 + lane) * 8);
#pragma unroll
        for (int r = 0; r < 4; ++r) lenr[r] = lengths[16 * wv + aq * 4 + r];
    }
    // store-duty decode (all 4 waves): stg[i], i = tid
    const int sloc = tid & 127;
    const int shw  = tid >> 7;                       // batch half
    const int sb   = shw * 16 + ((sloc >> 2) & 15);  // batch
    const int sq   = ((sloc >> 6) & 1) * 4 + (sloc & 3);
    const int spc  = sl * 8 + sq;                    // global j-pair column
    const int slen = lengths[sb];
    const int base0 = ((sl >> 1) << 8) + (((2 * sl) & 3) << 6);  // run base (dwords)

    int* myflags = flags + d * (256 * 64);
    unsigned int* Hst = Hstate + (size_t)d * 256 * 4096;
    const float* gin_d = Gin + (size_t)d * MROWS * GATES;

    for (int s = 0; s < 256; ++s) {
        const int t = d ? 255 - s : s;
        const int slot = (s * 37) & 255;

        float gv[4][4];
        if (comp) {
            // Gin prefetch (pure input; issued before the poll)
#pragma unroll
            for (int r = 0; r < 4; ++r) {
                const float* gp = gin_d + ((size_t)(16 * wv + aq * 4 + r) * Tv + t) * GATES
                                + sl * 16 + ar;
#pragma unroll
                for (int g = 0; g < 4; ++g) gv[g][r] = gp[g * 256];
            }
        }

        v4f acc[4];
#pragma unroll
        for (int g = 0; g < 4; ++g) acc[g] = (v4f){0.f, 0.f, 0.f, 0.f};

        if (s > 0 && comp) {
            const int pslot = ((s - 1) * 37) & 255;
            // hard-spin relaxed poll: lane l watches flag (slice*4+wave) = l
            {
                const int* fp = myflags + (s - 1) * 64 + lane;
                int spins = 0;
                while (__hip_atomic_load(fp, __ATOMIC_RELAXED, __HIP_MEMORY_SCOPE_AGENT) == 0) {
                    if (++spins > (1 << 22)) break;   // safety valve
                }
            }
            __asm__ __volatile__("" ::: "memory");    // no hoisting above poll
            // A fragments direct to registers: coalesced dwordx4 (no LDS)
            const uint4* Hp = (const uint4*)(Hst + (size_t)pslot * 4096) + wv * 512;
            uint4 afr[8];
#pragma unroll
            for (int kt = 0; kt < 8; ++kt) afr[kt] = Hp[kt * 64 + lane];
#pragma unroll
            for (int kt = 0; kt < 8; ++kt) {
                union { uint4 u; v8bf v; } a; a.u = afr[kt];
#pragma unroll
                for (int g = 0; g < 4; ++g)
                    acc[g] = __builtin_amdgcn_mfma_f32_16x16x32_bf16(a.v, wreg[g][kt], acc[g], 0, 0, 0);
            }
        }

        if (comp) {
            const int q = ar >> 1;
#pragma unroll
            for (int r = 0; r < 4; ++r) {
                float p0 = gv[0][r] + acc[0][r];
                float p1 = gv[1][r] + acc[1][r];
                float p2 = gv[2][r] + acc[2][r];
                float p3 = gv[3][r] + acc[3][r];
                float ig = sigf(p0), fg = sigf(p1);
                float gg = tanhf2(p2), og = sigf(p3);
                float cn = fg * cst[r] + ig * gg;
                float hn = og * tanhf2(cn);
                bool m = (t < lenr[r]);
                cst[r] = m ? cn : cst[r];
                hst[r] = m ? hn : hst[r];
            }
            // pack j-pairs via shfl, stage into fragment-local order
#pragma unroll
            for (int r = 0; r < 4; ++r) {
                float other = __shfl_xor(hst[r], 1);
                if ((ar & 1) == 0) {
                    unsigned int pk = (unsigned)f2bf(hst[r]) | ((unsigned)f2bf(other) << 16);
                    stg[wv * 128 + (q >> 2) * 64 + (aq * 4 + r) * 4 + (q & 3)] = pk;
                }
            }
        }
        __syncthreads();   // stg ready
        // all 4 waves: one contiguous 256B run each -> Hstate; Hout alongside
        {
            unsigned int pk = stg[tid];
            __hip_atomic_store(Hst + (size_t)slot * 4096 + (shw << 11) + base0 + sloc, pk,
                               __ATOMIC_RELAXED, __HIP_MEMORY_SCOPE_AGENT);
            Hout[((size_t)sb * Tv + t) * 256 + d * 128 + spc] = (t < slen) ? pk : 0u;
            __asm__ __volatile__("" ::: "memory");
            __builtin_amdgcn_s_waitcnt(0);            // wave-local drain to LLC
            __asm__ __volatile__("" ::: "memory");
            if (lane == 0)
                __hip_atomic_store(myflags + s * 64 + sl * 4 + wv, 1,
                                   __ATOMIC_RELAXED, __HIP_MEMORY_SCOPE_AGENT);
        }
    }
}

// ---------------- CRF ----------------
__global__ __launch_bounds__(64) void crf_kernel(
    const float* __restrict__ Y, const float* __restrict__ trans,
    const int* __restrict__ y0, const int* __restrict__ lengths,
    float* __restrict__ out) {
    int b = blockIdx.x, j = threadIdx.x;
    int len = lengths[b];
    float trj[64];
#pragma unroll
    for (int i = 0; i < 64; ++i) trj[i] = trans[j * 64 + i];
    __shared__ __align__(16) float s[64];
    s[j] = (j == 2) ? 0.f : -10000.f;
    __syncthreads();
    const float* yb = Y + (size_t)b * Tv * Kv;
    for (int t = 0; t < len; ++t) {
        float emit = yb[t * 64 + j];
        float m = -3.0e38f;
#pragma unroll
        for (int i = 0; i < 64; ++i) m = fmaxf(m, s[i] + trj[i]);
        float sum = 0.f;
#pragma unroll
        for (int i = 0; i < 64; ++i) sum += __expf(s[i] + trj[i] - m);
        float ns = m + __logf(sum) + emit;
        __syncthreads();
        s[j] = ns;
        __syncthreads();
    }
    float v = s[j];
    float M = v;
#pragma unroll
    for (int o = 32; o; o >>= 1) M = fmaxf(M, __shfl_xor(M, o));
    float e = __expf(v - M);
#pragma unroll
    for (int o = 32; o; o >>= 1) e += __shfl_xor(e, o);
    float Z = M + __logf(e);
    float gold = 0.f;
    for (int t = j; t < len; t += 64) {
        int yt = y0[b * Tv + t];
        int yp = (t == 0) ? 2 : y0[b * Tv + t - 1];
        gold += yb[t * 64 + yt] + trans[yt * 64 + yp];
    }
#pragma unroll
    for (int o = 32; o; o >>= 1) gold += __shfl_xor(gold, o);
    if (j == 0) out[b] = Z - gold;
}

// ---------------- host ----------------
extern "C" void kernel_launch(void* const* d_in, const int* in_sizes, int n_in,
                              void* d_out, int out_size, void* d_ws, size_t ws_size,
                              hipStream_t stream) {
    const int*   x     = (const int*)d_in[0];
    const float* f     = (const float*)d_in[1];
    const int*   y0    = (const int*)d_in[2];
    const float* embed = (const float*)d_in[3];
    const float* Wih0f = (const float*)d_in[4],  *Whh0f = (const float*)d_in[5];
    const float* bih0f = (const float*)d_in[6],  *bhh0f = (const float*)d_in[7];
    const float* Wih0b = (const float*)d_in[8],  *Whh0b = (const float*)d_in[9];
    const float* bih0b = (const float*)d_in[10], *bhh0b = (const float*)d_in[11];
    const float* Wih1f = (const float*)d_in[12], *Whh1f = (const float*)d_in[13];
    const float* bih1f = (const float*)d_in[14], *bhh1f = (const float*)d_in[15];
    const float* Wih1b = (const float*)d_in[16], *Whh1b = (const float*)d_in[17];
    const float* bih1b = (const float*)d_in[18], *bhh1b = (const float*)d_in[19];
    const float* out_w = (const float*)d_in[20];
    const float* out_b = (const float*)d_in[21];
    const float* trans = (const float*)d_in[22];

    char* ws = (char*)d_ws;
    size_t off = 0;
    auto alloc = [&](size_t bytes) -> void* {
        off = (off + 255) & ~(size_t)255;
        void* p = ws + off;
        off += bytes;
        return p;
    };
    unsigned short* X0   = (unsigned short*)alloc((size_t)MROWS * K0PAD * 2);
    unsigned short* dW0  = (unsigned short*)alloc((size_t)2 * 1024 * K0PAD * 2);
    unsigned short* dW1  = (unsigned short*)alloc((size_t)2 * 1024 * 512 * 2);
    unsigned short* dOW  = (unsigned short*)alloc((size_t)64 * 512 * 2);
    unsigned short* Wfrag= (unsigned short*)alloc((size_t)4 * NSLICE * WFRAG_PER_DS * 2);
    float*          bias = (float*)alloc((size_t)4096 * 4);
    int*            lens = (int*)alloc((size_t)32 * 4);
    int*            flags= (int*)alloc((size_t)2 * 2 * 256 * 64 * 4);
    unsigned int*   Hst0 = (unsigned int*)alloc((size_t)2 * 256 * 4096 * 4);
    unsigned int*   Hst1 = (unsigned int*)alloc((size_t)2 * 256 * 4096 * 4);
    float*          Gin  = (float*)alloc((size_t)2 * MROWS * GATES * 4);
    unsigned short* H0   = (unsigned short*)alloc((size_t)MROWS * 512 * 2);
    unsigned short* H1   = (unsigned short*)alloc((size_t)MROWS * 512 * 2);
    float*          Y    = (float*)alloc((size_t)MROWS * Kv * 4);
    (void)ws_size; (void)in_sizes; (void)n_in; (void)out_size;

    // prep
    conv_weights<<<dim3(2048, 1, 5), 256, 0, stream>>>(Wih0f, Wih0b, Wih1f, Wih1b, out_w,
                                                       dW0, dW1, dOW);
    whh_frag<<<dim3(1024, 1, 4), 256, 0, stream>>>(Whh0f, Whh0b, Whh1f, Whh1b, Wfrag);
    bias_sum<<<16, 256, 0, stream>>>(bih0f, bhh0f, bih0b, bhh0b,
                                     bih1f, bhh1f, bih1b, bhh1b, bias);
    calc_len<<<32, 256, 0, stream>>>(x, lens);
    zero_flags<<<256, 256, 0, stream>>>(flags);
    embed_pack<<<MROWS, 64, 0, stream>>>(x, f, embed, X0);

    // layer 0 (both dirs in one launch)
    mfma_gemm64<<<dim3(MROWS / 64, 16, 2), 64, 0, stream>>>(
        X0, K0PAD, dW0, K0PAD, 1024 * K0PAD, bias, 1024,
        Gin, GATES, (size_t)MROWS * GATES, K0PAD);
    lstm_slice<<<dim3(NSLICE, 2), 256, 0, stream>>>(Gin, Wfrag, Hst0,
                                                    (unsigned int*)H0, flags, lens);

    // layer 1
    mfma_gemm64<<<dim3(MROWS / 64, 16, 2), 64, 0, stream>>>(
        H0, 512, dW1, 512, 1024 * 512, bias + 2048, 1024,
        Gin, GATES, (size_t)MROWS * GATES, 512);
    lstm_slice<<<dim3(NSLICE, 2), 256, 0, stream>>>(Gin, Wfrag + (size_t)2 * NSLICE * WFRAG_PER_DS,
                                                    Hst1, (unsigned int*)H1,
                                                    flags + 2 * 256 * 64, lens);

    // emissions + CRF
    mfma_gemm64<<<dim3(MROWS / 64, 1, 1), 64, 0, stream>>>(
        H1, 512, dOW, 512, 0, out_b, 0, Y, Kv, 0, 512);
    crf_kernel<<<32, 64, 0, stream>>>(Y, trans, y0, lens, (float*)d_out);
}

// Round 7
// 2257.352 us; speedup vs baseline: 1.0067x; 1.0067x over previous
//
#include <hip/hip_runtime.h>
#include <hip/hip_bf16.h>

// ---------------------------------------------------------------------------
// LSTM-CRF forward on MI355X.
// R7 = R5 structure (4 compute waves gate-split, DMA-staged A, GT exchange)
// with a trimmed producer tail:
//  - update-phase thread remap -> each wave stores ONE contiguous 256B run
//    of the fragment-ordered h slot (write-through sc0 sc1).
//  - per-wave s_waitcnt vmcnt(0) + per-wave flag (3rd barrier deleted);
//    Hout store moved after the flag (next-dispatch consumer, stream-ordered).
//  - 2 barriers/step: (A) post-DMA, (B) post-GT. Proven-safe interleaving.
// GEMMs: R6's merged 64x64-per-wave tiles (measured -100us non-LSTM).
// ---------------------------------------------------------------------------

#define Bv 32
#define Tv 256
#define Ev 300
#define HDv 256
#define Kv 64
#define MROWS (Bv * Tv)          // 8192
#define K0PAD 320                // 301 padded to mult of 32
#define GATES 1024               // 4*HD
#define NSLICE 16                // j-slices per dir
#define JS 16                    // j per slice
#define WFRAG_PER_DS (4 * 8 * 64 * 8)   // shorts per (dir,slice) weight block

typedef __bf16 v8bf __attribute__((ext_vector_type(8)));
typedef float  v4f  __attribute__((ext_vector_type(4)));

__device__ __forceinline__ unsigned short f2bf(float f) {
    unsigned u = __float_as_uint(f);
    unsigned r = (u + 0x7fffu + ((u >> 16) & 1u)) >> 16;
    return (unsigned short)r;
}
__device__ __forceinline__ float sigf(float x) { return 1.0f / (1.0f + __expf(-x)); }
__device__ __forceinline__ float tanhf2(float x) {
    x = fminf(15.f, fmaxf(-15.f, x));
    float e = __expf(2.f * x);
    return (e - 1.f) / (e + 1.f);
}
__device__ __forceinline__ void gl_lds16(const unsigned int* g, unsigned int* l) {
    __builtin_amdgcn_global_load_lds(
        (const __attribute__((address_space(1))) unsigned int*)g,
        (__attribute__((address_space(3))) unsigned int*)l, 16, 0, 0);
}
__device__ __forceinline__ void sc_store(unsigned int* p, unsigned int v) {
    asm volatile("global_store_dword %0, %1, off sc0 sc1" :: "v"(p), "v"(v) : "memory");
}

// ---------------- prep kernels ----------------

__global__ void conv_weights(const float* w0f, const float* w0b,
                             const float* w1f, const float* w1b,
                             const float* outw,
                             unsigned short* dW0, unsigned short* dW1,
                             unsigned short* dOW) {
    int z = blockIdx.z;
    const float* src; unsigned short* dst; int rows, kin, kout;
    if (z == 0)      { src = w0f;  dst = dW0;                rows = 1024; kin = 301; kout = K0PAD; }
    else if (z == 1) { src = w0b;  dst = dW0 + 1024 * K0PAD; rows = 1024; kin = 301; kout = K0PAD; }
    else if (z == 2) { src = w1f;  dst = dW1;                rows = 1024; kin = 512; kout = 512; }
    else if (z == 3) { src = w1b;  dst = dW1 + 1024 * 512;   rows = 1024; kin = 512; kout = 512; }
    else             { src = outw; dst = dOW;                rows = 64;   kin = 512; kout = 512; }
    int idx = blockIdx.x * 256 + threadIdx.x;
    if (idx >= rows * kout) return;
    int j = idx / kout, k = idx - j * kout;
    dst[idx] = (k < kin) ? f2bf(src[j * kin + k]) : (unsigned short)0;
}

// Whh [1024,256] fp32 -> bf16 MFMA B-fragment order:
// per (layer*2+dir) z: [slice(16)][gate(4)][kt(8)][lane(64)][e(8)]
__global__ void whh_frag(const float* h0f, const float* h0b,
                         const float* h1f, const float* h1b, unsigned short* Wfrag) {
    int z = blockIdx.z;
    const float* src = (z == 0) ? h0f : (z == 1) ? h0b : (z == 2) ? h1f : h1b;
    unsigned short* dst = Wfrag + (size_t)z * (NSLICE * WFRAG_PER_DS);
    int idx = blockIdx.x * 256 + threadIdx.x;          // 0..262143
    int e = idx & 7, ln = (idx >> 3) & 63, kt = (idx >> 9) & 7;
    int g = (idx >> 12) & 3, sl = idx >> 14;
    int n = g * 256 + sl * JS + (ln & 15);
    int k = kt * 32 + (ln >> 4) * 8 + e;
    dst[idx] = f2bf(src[n * 256 + k]);
}

__global__ void bias_sum(const float* a0, const float* b0, const float* a1, const float* b1,
                         const float* a2, const float* b2, const float* a3, const float* b3,
                         float* bias) {
    int idx = blockIdx.x * 256 + threadIdx.x;      // 0..4095
    int dl = idx >> 10, j = idx & 1023;
    const float* A = (dl == 0) ? a0 : (dl == 1) ? a1 : (dl == 2) ? a2 : a3;
    const float* B = (dl == 0) ? b0 : (dl == 1) ? b1 : (dl == 2) ? b2 : b3;
    bias[idx] = A[j] + B[j];
}

__global__ void calc_len(const int* x, int* lengths) {
    __shared__ int cnt;
    if (threadIdx.x == 0) cnt = 0;
    __syncthreads();
    if (x[blockIdx.x * Tv + threadIdx.x] > 0) atomicAdd(&cnt, 1);
    __syncthreads();
    if (threadIdx.x == 0) lengths[blockIdx.x] = cnt;
}

__global__ void zero_flags(int* flags) {
    flags[blockIdx.x * 256 + threadIdx.x] = 0;
}

// X0 row = [embed[tok](300) | f(1) | zeros(19)] as bf16
__global__ void embed_pack(const int* __restrict__ x, const float* __restrict__ f,
                           const float* __restrict__ embed, unsigned short* __restrict__ X0) {
    int row = blockIdx.x;
    int tok = x[row];
    float fv = f[row];
    const float* e = embed + (size_t)tok * Ev;
    for (int k = threadIdx.x; k < K0PAD; k += 64) {
        float v = (k < Ev) ? e[k] : ((k == Ev) ? fv : 0.f);
        X0[(size_t)row * K0PAD + k] = f2bf(v);
    }
}

// ------- MFMA GEMM 64x64 per wave: C[M,N] = X[M,K] @ W[N,K]^T + bias[N] ----
__global__ __launch_bounds__(64) void mfma_gemm64(
    const unsigned short* __restrict__ X, int ldx,
    const unsigned short* __restrict__ Wt, int ldw, int wstride_z,
    const float* __restrict__ bias, int bstride_z,
    float* __restrict__ C, int ldc, size_t cstride_z, int K) {
    const int lane = threadIdx.x;
    const int z = blockIdx.z;
    const unsigned short* W = Wt + (size_t)z * wstride_z;
    const float* bz = bias + (size_t)z * bstride_z;
    float* Cz = C + (size_t)z * cstride_z;
    const int m0 = blockIdx.x * 64, n0 = blockIdx.y * 64;
    const int r = lane & 15, q = lane >> 4;
    const unsigned short* xp[4];
    const unsigned short* wp[4];
#pragma unroll
    for (int i = 0; i < 4; ++i) {
        xp[i] = X + (size_t)(m0 + 16 * i + r) * ldx + q * 8;
        wp[i] = W + (size_t)(n0 + 16 * i + r) * ldw + q * 8;
    }
    v4f acc[4][4];
#pragma unroll
    for (int i = 0; i < 4; ++i)
#pragma unroll
        for (int j = 0; j < 4; ++j) acc[i][j] = (v4f){0.f, 0.f, 0.f, 0.f};
#pragma unroll 2
    for (int k = 0; k < K; k += 32) {
        v8bf a[4], b[4];
#pragma unroll
        for (int i = 0; i < 4; ++i) { a[i] = *(const v8bf*)(xp[i] + k); b[i] = *(const v8bf*)(wp[i] + k); }
#pragma unroll
        for (int i = 0; i < 4; ++i)
#pragma unroll
            for (int j = 0; j < 4; ++j)
                acc[i][j] = __builtin_amdgcn_mfma_f32_16x16x32_bf16(a[i], b[j], acc[i][j], 0, 0, 0);
    }
#pragma unroll
    for (int j = 0; j < 4; ++j) {
        int col = n0 + 16 * j + r;
        float bv = bz[col];
#pragma unroll
        for (int i = 0; i < 4; ++i)
#pragma unroll
            for (int e = 0; e < 4; ++e)
                Cz[(size_t)(m0 + 16 * i + q * 4 + e) * ldc + col] = acc[i][j][e] + bv;
    }
}

// ---------------- slice-parallel LSTM (R7) ----------------
// Hstate slot (4096 dwords) = MFMA A-fragment order:
//   dword(b,pc) = (b&16)*128 + (pc>>4)*256 + ((pc>>2)&3)*64 + (b&15)*4 + (pc&3)
// b=batch, pc=global j-pair column. flags [dir][step][64] (slice*4+wave).
__global__ __launch_bounds__(256) void lstm_slice(
    const float* __restrict__ Gin,
    const unsigned short* __restrict__ Wfrag,
    unsigned int* __restrict__ Hstate,
    unsigned int* __restrict__ Hout,
    int* __restrict__ flags,
    const int* __restrict__ lengths) {
    const int d = blockIdx.y, sl = blockIdx.x;
    const int tid = threadIdx.x;
    const int lane = tid & 63, g = tid >> 6;

    __shared__ __align__(16) unsigned int Afrag[4096];   // 16 KB, fragment order
    __shared__ float GT[4][32][17];                      // gate staging (+pad)

    // Whh B-fragments -> registers (8 kt x 16B per lane; this wave's gate)
    v8bf wreg[8];
    {
        const unsigned short* wb = Wfrag + (size_t)(d * NSLICE + sl) * WFRAG_PER_DS
                                 + ((size_t)g * 8 * 64 + lane) * 8;
#pragma unroll
        for (int kt = 0; kt < 8; ++kt)
            wreg[kt] = *(const v8bf*)(wb + (size_t)kt * 64 * 8);
    }
    // update-phase mapping: wave-contiguous producer runs
    const int half = tid >> 7;                 // batch half
    const int rem  = tid & 127;
    const int b15  = (rem >> 2) & 15;
    const int jlow = rem & 3;
    const int jq   = rem >> 6;
    const int ub   = half * 16 + b15;          // batch
    const int ujp  = jq * 4 + jlow;            // local j-pair 0..7
    const int ulen = lengths[ub];
    const int B0   = ((sl >> 1) << 8) + ((2 * sl) & 3) * 64;
    const int pidx = half * 2048 + B0 + rem;   // wave-contiguous dword index
    float cA = 0.f, hA = 0.f, cB = 0.f, hB = 0.f;
    int* myflags = flags + d * (256 * 64);
    unsigned int* Hst = Hstate + (size_t)d * 256 * 4096;
    const float* gin_d = Gin + (size_t)d * MROWS * GATES;
    const int ar = lane & 15, aq = lane >> 4;

    for (int s = 0; s < 256; ++s) {
        const int t = d ? 255 - s : s;
        const int slot = (s * 37) & 255;
        // Gin prefetch (independent of flags; issues before polling)
        float2 gv[4];
        const float2* gp = (const float2*)(gin_d + ((size_t)ub * Tv + t) * GATES
                                           + sl * 16 + 2 * ujp);
#pragma unroll
        for (int q = 0; q < 4; ++q) gv[q] = gp[q * 128];

        if (s > 0) {
            const int pslot = ((s - 1) * 37) & 255;
            // hard-spin relaxed poll: lane l watches flag (slice*4+wave) = l
            {
                const int* fp = myflags + (s - 1) * 64 + lane;
                int spins = 0;
                while (__hip_atomic_load(fp, __ATOMIC_RELAXED, __HIP_MEMORY_SCOPE_AGENT) == 0) {
                    if (++spins > (1 << 22)) break;   // safety valve
                }
            }
            __asm__ __volatile__("" ::: "memory");    // no hoisting above poll
            // stage h(t-1): 16 KB contiguous via global_load_lds, 4 segs/wave
            const unsigned int* Hp = Hst + (size_t)pslot * 4096;
#pragma unroll
            for (int i = 0; i < 4; ++i) {
                int seg = g * 4 + i;
                gl_lds16(Hp + (seg * 64 + lane) * 4, &Afrag[seg * 256]);
            }
            __syncthreads();                          // (A) DMA drained: Afrag ready
            // fragments + MFMA (A shared by all 4 waves; B in registers)
            v4f acc0 = {0.f, 0.f, 0.f, 0.f}, acc1 = acc0;
            const uint4* Af = (const uint4*)Afrag;
#pragma unroll
            for (int kt = 0; kt < 8; ++kt) {
                union { uint4 u; v8bf v; } c0, c1;
                c0.u = Af[kt * 64 + lane];
                c1.u = Af[512 + kt * 64 + lane];
                acc0 = __builtin_amdgcn_mfma_f32_16x16x32_bf16(c0.v, wreg[kt], acc0, 0, 0, 0);
                acc1 = __builtin_amdgcn_mfma_f32_16x16x32_bf16(c1.v, wreg[kt], acc1, 0, 0, 0);
            }
#pragma unroll
            for (int r = 0; r < 4; ++r) {          // C: col=lane&15 (j), row=quad*4+r (b)
                GT[g][aq * 4 + r][ar]      = acc0[r];
                GT[g][16 + aq * 4 + r][ar] = acc1[r];
            }
            __syncthreads();                          // (B) GT ready
        }
        // update (b=ub, j = sl*16 + 2*ujp and +1); state in registers
        {
            float pA[4], pB[4];
#pragma unroll
            for (int q = 0; q < 4; ++q) {
                float rA = (s > 0) ? GT[q][ub][2 * ujp]     : 0.f;
                float rB = (s > 0) ? GT[q][ub][2 * ujp + 1] : 0.f;
                pA[q] = gv[q].x + rA;
                pB[q] = gv[q].y + rB;
            }
            bool m = (t < ulen);
            {
                float ig = sigf(pA[0]), fg = sigf(pA[1]);
                float gg = tanhf2(pA[2]), og = sigf(pA[3]);
                float cn = fg * cA + ig * gg;
                float hn = og * tanhf2(cn);
                cA = m ? cn : cA; hA = m ? hn : hA;
            }
            {
                float ig = sigf(pB[0]), fg = sigf(pB[1]);
                float gg = tanhf2(pB[2]), og = sigf(pB[3]);
                float cn = fg * cB + ig * gg;
                float hn = og * tanhf2(cn);
                cB = m ? cn : cB; hB = m ? hn : hB;
            }
            unsigned int pk = (unsigned)f2bf(hA) | ((unsigned)f2bf(hB) << 16);
            // wave-contiguous write-through h store (256B burst per wave)
            sc_store(Hst + (size_t)slot * 4096 + pidx, pk);
            __asm__ __volatile__("s_waitcnt vmcnt(0)" ::: "memory");
            if (lane == 0)
                sc_store((unsigned int*)(myflags + s * 64 + sl * 4 + g), 1u);
            // Hout after the flag: consumed by the NEXT dispatch (stream order)
            Hout[((size_t)ub * Tv + t) * 256 + d * 128 + sl * 8 + ujp] = m ? pk : 0u;
        }
        // no 3rd barrier: DMA(s+1) targets Afrag only after barrier (A) of s+1,
        // and GT(s+1) writes only after all waves pass (A) -> no WAR hazards.
    }
}

// ---------------- CRF ----------------
__global__ __launch_bounds__(64) void crf_kernel(
    const float* __restrict__ Y, const float* __restrict__ trans,
    const int* __restrict__ y0, const int* __restrict__ lengths,
    float* __restrict__ out) {
    int b = blockIdx.x, j = threadIdx.x;
    int len = lengths[b];
    float trj[64];
#pragma unroll
    for (int i = 0; i < 64; ++i) trj[i] = trans[j * 64 + i];
    __shared__ __align__(16) float s[64];
    s[j] = (j == 2) ? 0.f : -10000.f;
    __syncthreads();
    const float* yb = Y + (size_t)b * Tv * Kv;
    for (int t = 0; t < len; ++t) {
        float emit = yb[t * 64 + j];
        float m = -3.0e38f;
#pragma unroll
        for (int i = 0; i < 64; ++i) m = fmaxf(m, s[i] + trj[i]);
        float sum = 0.f;
#pragma unroll
        for (int i = 0; i < 64; ++i) sum += __expf(s[i] + trj[i] - m);
        float ns = m + __logf(sum) + emit;
        __syncthreads();
        s[j] = ns;
        __syncthreads();
    }
    float v = s[j];
    float M = v;
#pragma unroll
    for (int o = 32; o; o >>= 1) M = fmaxf(M, __shfl_xor(M, o));
    float e = __expf(v - M);
#pragma unroll
    for (int o = 32; o; o >>= 1) e += __shfl_xor(e, o);
    float Z = M + __logf(e);
    float gold = 0.f;
    for (int t = j; t < len; t += 64) {
        int yt = y0[b * Tv + t];
        int yp = (t == 0) ? 2 : y0[b * Tv + t - 1];
        gold += yb[t * 64 + yt] + trans[yt * 64 + yp];
    }
#pragma unroll
    for (int o = 32; o; o >>= 1) gold += __shfl_xor(gold, o);
    if (j == 0) out[b] = Z - gold;
}

// ---------------- host ----------------
extern "C" void kernel_launch(void* const* d_in, const int* in_sizes, int n_in,
                              void* d_out, int out_size, void* d_ws, size_t ws_size,
                              hipStream_t stream) {
    const int*   x     = (const int*)d_in[0];
    const float* f     = (const float*)d_in[1];
    const int*   y0    = (const int*)d_in[2];
    const float* embed = (const float*)d_in[3];
    const float* Wih0f = (const float*)d_in[4],  *Whh0f = (const float*)d_in[5];
    const float* bih0f = (const float*)d_in[6],  *bhh0f = (const float*)d_in[7];
    const float* Wih0b = (const float*)d_in[8],  *Whh0b = (const float*)d_in[9];
    const float* bih0b = (const float*)d_in[10], *bhh0b = (const float*)d_in[11];
    const float* Wih1f = (const float*)d_in[12], *Whh1f = (const float*)d_in[13];
    const float* bih1f = (const float*)d_in[14], *bhh1f = (const float*)d_in[15];
    const float* Wih1b = (const float*)d_in[16], *Whh1b = (const float*)d_in[17];
    const float* bih1b = (const float*)d_in[18], *bhh1b = (const float*)d_in[19];
    const float* out_w = (const float*)d_in[20];
    const float* out_b = (const float*)d_in[21];
    const float* trans = (const float*)d_in[22];

    char* ws = (char*)d_ws;
    size_t off = 0;
    auto alloc = [&](size_t bytes) -> void* {
        off = (off + 255) & ~(size_t)255;
        void* p = ws + off;
        off += bytes;
        return p;
    };
    unsigned short* X0   = (unsigned short*)alloc((size_t)MROWS * K0PAD * 2);
    unsigned short* dW0  = (unsigned short*)alloc((size_t)2 * 1024 * K0PAD * 2);
    unsigned short* dW1  = (unsigned short*)alloc((size_t)2 * 1024 * 512 * 2);
    unsigned short* dOW  = (unsigned short*)alloc((size_t)64 * 512 * 2);
    unsigned short* Wfrag= (unsigned short*)alloc((size_t)4 * NSLICE * WFRAG_PER_DS * 2);
    float*          bias = (float*)alloc((size_t)4096 * 4);
    int*            lens = (int*)alloc((size_t)32 * 4);
    int*            flags= (int*)alloc((size_t)2 * 2 * 256 * 64 * 4);
    unsigned int*   Hst0 = (unsigned int*)alloc((size_t)2 * 256 * 4096 * 4);
    unsigned int*   Hst1 = (unsigned int*)alloc((size_t)2 * 256 * 4096 * 4);
    float*          Gin  = (float*)alloc((size_t)2 * MROWS * GATES * 4);
    unsigned short* H0   = (unsigned short*)alloc((size_t)MROWS * 512 * 2);
    unsigned short* H1   = (unsigned short*)alloc((size_t)MROWS * 512 * 2);
    float*          Y    = (float*)alloc((size_t)MROWS * Kv * 4);
    (void)ws_size; (void)in_sizes; (void)n_in; (void)out_size;

    // prep
    conv_weights<<<dim3(2048, 1, 5), 256, 0, stream>>>(Wih0f, Wih0b, Wih1f, Wih1b, out_w,
                                                       dW0, dW1, dOW);
    whh_frag<<<dim3(1024, 1, 4), 256, 0, stream>>>(Whh0f, Whh0b, Whh1f, Whh1b, Wfrag);
    bias_sum<<<16, 256, 0, stream>>>(bih0f, bhh0f, bih0b, bhh0b,
                                     bih1f, bhh1f, bih1b, bhh1b, bias);
    calc_len<<<32, 256, 0, stream>>>(x, lens);
    zero_flags<<<256, 256, 0, stream>>>(flags);
    embed_pack<<<MROWS, 64, 0, stream>>>(x, f, embed, X0);

    // layer 0 (both dirs in one launch)
    mfma_gemm64<<<dim3(MROWS / 64, 16, 2), 64, 0, stream>>>(
        X0, K0PAD, dW0, K0PAD, 1024 * K0PAD, bias, 1024,
        Gin, GATES, (size_t)MROWS * GATES, K0PAD);
    lstm_slice<<<dim3(NSLICE, 2), 256, 0, stream>>>(Gin, Wfrag, Hst0,
                                                    (unsigned int*)H0, flags, lens);

    // layer 1
    mfma_gemm64<<<dim3(MROWS / 64, 16, 2), 64, 0, stream>>>(
        H0, 512, dW1, 512, 1024 * 512, bias + 2048, 1024,
        Gin, GATES, (size_t)MROWS * GATES, 512);
    lstm_slice<<<dim3(NSLICE, 2), 256, 0, stream>>>(Gin, Wfrag + (size_t)2 * NSLICE * WFRAG_PER_DS,
                                                    Hst1, (unsigned int*)H1,
                                                    flags + 2 * 256 * 64, lens);

    // emissions + CRF
    mfma_gemm64<<<dim3(MROWS / 64, 1, 1), 64, 0, stream>>>(
        H1, 512, dOW, 512, 0, out_b, 0, Y, Kv, 0, 512);
    crf_kernel<<<32, 64, 0, stream>>>(Y, trans, y0, lens, (float*)d_out);
}

// Round 8
// 1688.860 us; speedup vs baseline: 1.3455x; 1.3366x over previous
//
#include <hip/hip_runtime.h>
#include <hip/hip_bf16.h>

// ---------------------------------------------------------------------------
// LSTM-CRF forward on MI355X.
// R8 = R5's lstm_slice VERBATIM (best measured: 605us/dispatch, 2.36us/step)
//      + R6/R7's merged mfma_gemm64 (validated -80us non-LSTM).
// R6/R7 post-mortem: per-wave flags + wave-local waitcnt + sc0sc1 stores all
// regressed vs R5's block-barrier drain + single flag/slice + 16-flag poll.
// ---------------------------------------------------------------------------

#define Bv 32
#define Tv 256
#define Ev 300
#define HDv 256
#define Kv 64
#define MROWS (Bv * Tv)          // 8192
#define K0PAD 320                // 301 padded to mult of 32
#define GATES 1024               // 4*HD
#define NSLICE 16                // j-slices per dir
#define JS 16                    // j per slice
#define FLAGSTRIDE 32            // dwords per step (128B line)
#define WFRAG_PER_DS (4 * 8 * 64 * 8)   // shorts per (dir,slice) weight block

typedef __bf16 v8bf __attribute__((ext_vector_type(8)));
typedef float  v4f  __attribute__((ext_vector_type(4)));

__device__ __forceinline__ unsigned short f2bf(float f) {
    unsigned u = __float_as_uint(f);
    unsigned r = (u + 0x7fffu + ((u >> 16) & 1u)) >> 16;
    return (unsigned short)r;
}
__device__ __forceinline__ float sigf(float x) { return 1.0f / (1.0f + __expf(-x)); }
__device__ __forceinline__ float tanhf2(float x) {
    x = fminf(15.f, fmaxf(-15.f, x));
    float e = __expf(2.f * x);
    return (e - 1.f) / (e + 1.f);
}
__device__ __forceinline__ void gl_lds16(const unsigned int* g, unsigned int* l) {
    __builtin_amdgcn_global_load_lds(
        (const __attribute__((address_space(1))) unsigned int*)g,
        (__attribute__((address_space(3))) unsigned int*)l, 16, 0, 0);
}

// ---------------- prep kernels ----------------

__global__ void conv_weights(const float* w0f, const float* w0b,
                             const float* w1f, const float* w1b,
                             const float* outw,
                             unsigned short* dW0, unsigned short* dW1,
                             unsigned short* dOW) {
    int z = blockIdx.z;
    const float* src; unsigned short* dst; int rows, kin, kout;
    if (z == 0)      { src = w0f;  dst = dW0;                rows = 1024; kin = 301; kout = K0PAD; }
    else if (z == 1) { src = w0b;  dst = dW0 + 1024 * K0PAD; rows = 1024; kin = 301; kout = K0PAD; }
    else if (z == 2) { src = w1f;  dst = dW1;                rows = 1024; kin = 512; kout = 512; }
    else if (z == 3) { src = w1b;  dst = dW1 + 1024 * 512;   rows = 1024; kin = 512; kout = 512; }
    else             { src = outw; dst = dOW;                rows = 64;   kin = 512; kout = 512; }
    int idx = blockIdx.x * 256 + threadIdx.x;
    if (idx >= rows * kout) return;
    int j = idx / kout, k = idx - j * kout;
    dst[idx] = (k < kin) ? f2bf(src[j * kin + k]) : (unsigned short)0;
}

// Whh [1024,256] fp32 -> bf16 MFMA B-fragment order:
// per (layer*2+dir) z: [slice(16)][gate(4)][kt(8)][lane(64)][e(8)]
// value = Whh[gate*256 + slice*16 + (lane&15)][kt*32 + (lane>>4)*8 + e]
__global__ void whh_frag(const float* h0f, const float* h0b,
                         const float* h1f, const float* h1b, unsigned short* Wfrag) {
    int z = blockIdx.z;
    const float* src = (z == 0) ? h0f : (z == 1) ? h0b : (z == 2) ? h1f : h1b;
    unsigned short* dst = Wfrag + (size_t)z * (NSLICE * WFRAG_PER_DS);
    int idx = blockIdx.x * 256 + threadIdx.x;          // 0..262143
    int e = idx & 7, ln = (idx >> 3) & 63, kt = (idx >> 9) & 7;
    int g = (idx >> 12) & 3, sl = idx >> 14;
    int n = g * 256 + sl * JS + (ln & 15);
    int k = kt * 32 + (ln >> 4) * 8 + e;
    dst[idx] = f2bf(src[n * 256 + k]);
}

__global__ void bias_sum(const float* a0, const float* b0, const float* a1, const float* b1,
                         const float* a2, const float* b2, const float* a3, const float* b3,
                         float* bias) {
    int idx = blockIdx.x * 256 + threadIdx.x;      // 0..4095
    int dl = idx >> 10, j = idx & 1023;
    const float* A = (dl == 0) ? a0 : (dl == 1) ? a1 : (dl == 2) ? a2 : a3;
    const float* B = (dl == 0) ? b0 : (dl == 1) ? b1 : (dl == 2) ? b2 : b3;
    bias[idx] = A[j] + B[j];
}

__global__ void calc_len(const int* x, int* lengths) {
    __shared__ int cnt;
    if (threadIdx.x == 0) cnt = 0;
    __syncthreads();
    if (x[blockIdx.x * Tv + threadIdx.x] > 0) atomicAdd(&cnt, 1);
    __syncthreads();
    if (threadIdx.x == 0) lengths[blockIdx.x] = cnt;
}

__global__ void zero_flags(int* flags) {
    flags[blockIdx.x * 256 + threadIdx.x] = 0;
}

// X0 row = [embed[tok](300) | f(1) | zeros(19)] as bf16
__global__ void embed_pack(const int* __restrict__ x, const float* __restrict__ f,
                           const float* __restrict__ embed, unsigned short* __restrict__ X0) {
    int row = blockIdx.x;
    int tok = x[row];
    float fv = f[row];
    const float* e = embed + (size_t)tok * Ev;
    for (int k = threadIdx.x; k < K0PAD; k += 64) {
        float v = (k < Ev) ? e[k] : ((k == Ev) ? fv : 0.f);
        X0[(size_t)row * K0PAD + k] = f2bf(v);
    }
}

// ------- MFMA GEMM 64x64 per wave: C[M,N] = X[M,K] @ W[N,K]^T + bias[N] ----
__global__ __launch_bounds__(64) void mfma_gemm64(
    const unsigned short* __restrict__ X, int ldx,
    const unsigned short* __restrict__ Wt, int ldw, int wstride_z,
    const float* __restrict__ bias, int bstride_z,
    float* __restrict__ C, int ldc, size_t cstride_z, int K) {
    const int lane = threadIdx.x;
    const int z = blockIdx.z;
    const unsigned short* W = Wt + (size_t)z * wstride_z;
    const float* bz = bias + (size_t)z * bstride_z;
    float* Cz = C + (size_t)z * cstride_z;
    const int m0 = blockIdx.x * 64, n0 = blockIdx.y * 64;
    const int r = lane & 15, q = lane >> 4;
    const unsigned short* xp[4];
    const unsigned short* wp[4];
#pragma unroll
    for (int i = 0; i < 4; ++i) {
        xp[i] = X + (size_t)(m0 + 16 * i + r) * ldx + q * 8;
        wp[i] = W + (size_t)(n0 + 16 * i + r) * ldw + q * 8;
    }
    v4f acc[4][4];
#pragma unroll
    for (int i = 0; i < 4; ++i)
#pragma unroll
        for (int j = 0; j < 4; ++j) acc[i][j] = (v4f){0.f, 0.f, 0.f, 0.f};
#pragma unroll 2
    for (int k = 0; k < K; k += 32) {
        v8bf a[4], b[4];
#pragma unroll
        for (int i = 0; i < 4; ++i) { a[i] = *(const v8bf*)(xp[i] + k); b[i] = *(const v8bf*)(wp[i] + k); }
#pragma unroll
        for (int i = 0; i < 4; ++i)
#pragma unroll
            for (int j = 0; j < 4; ++j)
                acc[i][j] = __builtin_amdgcn_mfma_f32_16x16x32_bf16(a[i], b[j], acc[i][j], 0, 0, 0);
    }
#pragma unroll
    for (int j = 0; j < 4; ++j) {
        int col = n0 + 16 * j + r;
        float bv = bz[col];
#pragma unroll
        for (int i = 0; i < 4; ++i)
#pragma unroll
            for (int e = 0; e < 4; ++e)
                Cz[(size_t)(m0 + 16 * i + q * 4 + e) * ldc + col] = acc[i][j][e] + bv;
    }
}

// ---------------- slice-parallel LSTM (R5 verbatim) ----------------
// Hstate slot layout = MFMA A-fragment order (4096 dwords):
//   dword(r,c) = (r>=16 ? 2048 : 0) + ((c>>4)*64 + ((c>>2)&3)*16 + (r&15))*4 + (c&3)
// where r=batch, c=packed j-pair column (j = 2c, 2c+1).
__global__ __launch_bounds__(256) void lstm_slice(
    const float* __restrict__ Gin,
    const unsigned short* __restrict__ Wfrag,
    unsigned int* __restrict__ Hstate,
    unsigned int* __restrict__ Hout,
    int* __restrict__ flags,
    const int* __restrict__ lengths) {
    const int d = blockIdx.y, sl = blockIdx.x;
    const int tid = threadIdx.x;
    const int lane = tid & 63, g = tid >> 6;
    const int j0 = sl * JS;

    __shared__ __align__(16) unsigned int Afrag[4096];   // 16 KB, fragment order
    __shared__ float GT[4][32][17];                      // gate staging (+pad)

    // Whh B-fragments -> registers (8 kt x 16B per lane)
    v8bf wreg[8];
    {
        const unsigned short* wb = Wfrag + (size_t)(d * NSLICE + sl) * WFRAG_PER_DS
                                 + ((size_t)g * 8 * 64 + lane) * 8;
#pragma unroll
        for (int kt = 0; kt < 8; ++kt)
            wreg[kt] = *(const v8bf*)(wb + (size_t)kt * 64 * 8);
    }
    // update-role mapping: one batch, two adjacent j
    const int ub = tid & 31, ujp = tid >> 5;                  // b, j-pair (0..7)
    const int ulen = lengths[ub];
    float cA = 0.f, hA = 0.f, cB = 0.f, hB = 0.f;
    int* myflags = flags + d * (256 * FLAGSTRIDE);
    unsigned int* Hst = Hstate + (size_t)d * 256 * 4096;
    const float* gin_d = Gin + (size_t)d * MROWS * GATES;
    // producer fragment-index for (ub, c=sl*8+ujp)
    const int pc = sl * 8 + ujp;
    const int pidx = ((ub & 16) ? 2048 : 0)
                   + (((pc >> 4) * 64 + ((pc >> 2) & 3) * 16 + (ub & 15)) << 2) + (pc & 3);

    for (int s = 0; s < 256; ++s) {
        const int t = d ? 255 - s : s;
        const int slot = (s * 37) & 255;
        // Gin prefetch (independent of flags; issues before polling)
        float2 gv[4];
        const float2* gp = (const float2*)(gin_d + ((size_t)ub * Tv + t) * GATES + j0 + 2 * ujp);
#pragma unroll
        for (int q = 0; q < 4; ++q) gv[q] = gp[q * 128];

        if (s > 0) {
            const int pslot = ((s - 1) * 37) & 255;
            // hard-spin relaxed poll: lanes<16 of every wave watch 16 slice flags
            if (lane < 16) {
                const int* fp = myflags + (s - 1) * FLAGSTRIDE + lane;
                int spins = 0;
                while (__hip_atomic_load(fp, __ATOMIC_RELAXED, __HIP_MEMORY_SCOPE_AGENT) == 0) {
                    if (++spins > (1 << 22)) break;   // safety valve
                }
            }
            __asm__ __volatile__("" ::: "memory");    // no hoisting above poll
            // stage h(t-1): 16 KB contiguous via global_load_lds, 4 segs/wave
            const unsigned int* Hp = Hst + (size_t)pslot * 4096;
#pragma unroll
            for (int i = 0; i < 4; ++i) {
                int seg = g * 4 + i;
                gl_lds16(Hp + (seg * 64 + lane) * 4, &Afrag[seg * 256]);
            }
            __syncthreads();                          // drains vmcnt: Afrag ready
            // fragments + MFMA (A shared by all 4 waves; B in registers)
            v4f acc0 = {0.f, 0.f, 0.f, 0.f}, acc1 = acc0;
            const uint4* Af = (const uint4*)Afrag;
#pragma unroll
            for (int kt = 0; kt < 8; ++kt) {
                union { uint4 u; v8bf v; } c0, c1;
                c0.u = Af[kt * 64 + lane];
                c1.u = Af[512 + kt * 64 + lane];
                acc0 = __builtin_amdgcn_mfma_f32_16x16x32_bf16(c0.v, wreg[kt], acc0, 0, 0, 0);
                acc1 = __builtin_amdgcn_mfma_f32_16x16x32_bf16(c1.v, wreg[kt], acc1, 0, 0, 0);
            }
            const int ar = lane & 15, aq = lane >> 4;
#pragma unroll
            for (int r = 0; r < 4; ++r) {          // C: col=lane&15 (j), row=quad*4+r (b)
                GT[g][aq * 4 + r][ar]      = acc0[r];
                GT[g][16 + aq * 4 + r][ar] = acc1[r];
            }
            __syncthreads();
        }
        // update (b=ub, j = j0+2*ujp and +1); state in registers
        unsigned int pk;
        {
            float pA[4], pB[4];
#pragma unroll
            for (int q = 0; q < 4; ++q) {
                float rA = (s > 0) ? GT[q][ub][2 * ujp]     : 0.f;
                float rB = (s > 0) ? GT[q][ub][2 * ujp + 1] : 0.f;
                pA[q] = gv[q].x + rA;
                pB[q] = gv[q].y + rB;
            }
            bool m = (t < ulen);
            {
                float ig = sigf(pA[0]), fg = sigf(pA[1]);
                float gg = tanhf2(pA[2]), og = sigf(pA[3]);
                float cn = fg * cA + ig * gg;
                float hn = og * tanhf2(cn);
                cA = m ? cn : cA; hA = m ? hn : hA;
            }
            {
                float ig = sigf(pB[0]), fg = sigf(pB[1]);
                float gg = tanhf2(pB[2]), og = sigf(pB[3]);
                float cn = fg * cB + ig * gg;
                float hn = og * tanhf2(cn);
                cB = m ? cn : cB; hB = m ? hn : hB;
            }
            pk = (unsigned)f2bf(hA) | ((unsigned)f2bf(hB) << 16);
            __hip_atomic_store(Hst + (size_t)slot * 4096 + pidx, pk,
                               __ATOMIC_RELAXED, __HIP_MEMORY_SCOPE_AGENT);
        }
        __syncthreads();   // vmcnt(0) drain: all waves' h stores at coherence point
        if (tid == 0)
            __hip_atomic_store(myflags + s * FLAGSTRIDE + sl, 1,
                               __ATOMIC_RELAXED, __HIP_MEMORY_SCOPE_AGENT);
        // Hout off the critical path (consumed by next dispatch only)
        {
            bool m = (t < ulen);
            Hout[((size_t)ub * Tv + t) * 256 + d * 128 + sl * 8 + ujp] = m ? pk : 0u;
        }
    }
}

// ---------------- CRF ----------------
__global__ __launch_bounds__(64) void crf_kernel(
    const float* __restrict__ Y, const float* __restrict__ trans,
    const int* __restrict__ y0, const int* __restrict__ lengths,
    float* __restrict__ out) {
    int b = blockIdx.x, j = threadIdx.x;
    int len = lengths[b];
    float trj[64];
#pragma unroll
    for (int i = 0; i < 64; ++i) trj[i] = trans[j * 64 + i];
    __shared__ __align__(16) float s[64];
    s[j] = (j == 2) ? 0.f : -10000.f;
    __syncthreads();
    const float* yb = Y + (size_t)b * Tv * Kv;
    for (int t = 0; t < len; ++t) {
        float emit = yb[t * 64 + j];
        float m = -3.0e38f;
#pragma unroll
        for (int i = 0; i < 64; ++i) m = fmaxf(m, s[i] + trj[i]);
        float sum = 0.f;
#pragma unroll
        for (int i = 0; i < 64; ++i) sum += __expf(s[i] + trj[i] - m);
        float ns = m + __logf(sum) + emit;
        __syncthreads();
        s[j] = ns;
        __syncthreads();
    }
    float v = s[j];
    float M = v;
#pragma unroll
    for (int o = 32; o; o >>= 1) M = fmaxf(M, __shfl_xor(M, o));
    float e = __expf(v - M);
#pragma unroll
    for (int o = 32; o; o >>= 1) e += __shfl_xor(e, o);
    float Z = M + __logf(e);
    float gold = 0.f;
    for (int t = j; t < len; t += 64) {
        int yt = y0[b * Tv + t];
        int yp = (t == 0) ? 2 : y0[b * Tv + t - 1];
        gold += yb[t * 64 + yt] + trans[yt * 64 + yp];
    }
#pragma unroll
    for (int o = 32; o; o >>= 1) gold += __shfl_xor(gold, o);
    if (j == 0) out[b] = Z - gold;
}

// ---------------- host ----------------
extern "C" void kernel_launch(void* const* d_in, const int* in_sizes, int n_in,
                              void* d_out, int out_size, void* d_ws, size_t ws_size,
                              hipStream_t stream) {
    const int*   x     = (const int*)d_in[0];
    const float* f     = (const float*)d_in[1];
    const int*   y0    = (const int*)d_in[2];
    const float* embed = (const float*)d_in[3];
    const float* Wih0f = (const float*)d_in[4],  *Whh0f = (const float*)d_in[5];
    const float* bih0f = (const float*)d_in[6],  *bhh0f = (const float*)d_in[7];
    const float* Wih0b = (const float*)d_in[8],  *Whh0b = (const float*)d_in[9];
    const float* bih0b = (const float*)d_in[10], *bhh0b = (const float*)d_in[11];
    const float* Wih1f = (const float*)d_in[12], *Whh1f = (const float*)d_in[13];
    const float* bih1f = (const float*)d_in[14], *bhh1f = (const float*)d_in[15];
    const float* Wih1b = (const float*)d_in[16], *Whh1b = (const float*)d_in[17];
    const float* bih1b = (const float*)d_in[18], *bhh1b = (const float*)d_in[19];
    const float* out_w = (const float*)d_in[20];
    const float* out_b = (const float*)d_in[21];
    const float* trans = (const float*)d_in[22];

    char* ws = (char*)d_ws;
    size_t off = 0;
    auto alloc = [&](size_t bytes) -> void* {
        off = (off + 255) & ~(size_t)255;
        void* p = ws + off;
        off += bytes;
        return p;
    };
    unsigned short* X0   = (unsigned short*)alloc((size_t)MROWS * K0PAD * 2);
    unsigned short* dW0  = (unsigned short*)alloc((size_t)2 * 1024 * K0PAD * 2);
    unsigned short* dW1  = (unsigned short*)alloc((size_t)2 * 1024 * 512 * 2);
    unsigned short* dOW  = (unsigned short*)alloc((size_t)64 * 512 * 2);
    unsigned short* Wfrag= (unsigned short*)alloc((size_t)4 * NSLICE * WFRAG_PER_DS * 2);
    float*          bias = (float*)alloc((size_t)4096 * 4);
    int*            lens = (int*)alloc((size_t)32 * 4);
    int*            flags= (int*)alloc((size_t)2 * 2 * 256 * FLAGSTRIDE * 4);
    unsigned int*   Hst0 = (unsigned int*)alloc((size_t)2 * 256 * 4096 * 4);
    unsigned int*   Hst1 = (unsigned int*)alloc((size_t)2 * 256 * 4096 * 4);
    float*          Gin  = (float*)alloc((size_t)2 * MROWS * GATES * 4);
    unsigned short* H0   = (unsigned short*)alloc((size_t)MROWS * 512 * 2);
    unsigned short* H1   = (unsigned short*)alloc((size_t)MROWS * 512 * 2);
    float*          Y    = (float*)alloc((size_t)MROWS * Kv * 4);
    (void)ws_size; (void)in_sizes; (void)n_in; (void)out_size;

    // prep
    conv_weights<<<dim3(2048, 1, 5), 256, 0, stream>>>(Wih0f, Wih0b, Wih1f, Wih1b, out_w,
                                                       dW0, dW1, dOW);
    whh_frag<<<dim3(1024, 1, 4), 256, 0, stream>>>(Whh0f, Whh0b, Whh1f, Whh1b, Wfrag);
    bias_sum<<<16, 256, 0, stream>>>(bih0f, bhh0f, bih0b, bhh0b,
                                     bih1f, bhh1f, bih1b, bhh1b, bias);
    calc_len<<<32, 256, 0, stream>>>(x, lens);
    zero_flags<<<128, 256, 0, stream>>>(flags);
    embed_pack<<<MROWS, 64, 0, stream>>>(x, f, embed, X0);

    // layer 0 (both dirs in one launch)
    mfma_gemm64<<<dim3(MROWS / 64, 16, 2), 64, 0, stream>>>(
        X0, K0PAD, dW0, K0PAD, 1024 * K0PAD, bias, 1024,
        Gin, GATES, (size_t)MROWS * GATES, K0PAD);
    lstm_slice<<<dim3(NSLICE, 2), 256, 0, stream>>>(Gin, Wfrag, Hst0,
                                                    (unsigned int*)H0, flags, lens);

    // layer 1
    mfma_gemm64<<<dim3(MROWS / 64, 16, 2), 64, 0, stream>>>(
        H0, 512, dW1, 512, 1024 * 512, bias + 2048, 1024,
        Gin, GATES, (size_t)MROWS * GATES, 512);
    lstm_slice<<<dim3(NSLICE, 2), 256, 0, stream>>>(Gin, Wfrag + (size_t)2 * NSLICE * WFRAG_PER_DS,
                                                    Hst1, (unsigned int*)H1,
                                                    flags + 2 * 256 * FLAGSTRIDE, lens);

    // emissions + CRF
    mfma_gemm64<<<dim3(MROWS / 64, 1, 1), 64, 0, stream>>>(
        H1, 512, dOW, 512, 0, out_b, 0, Y, Kv, 0, 512);
    crf_kernel<<<32, 64, 0, stream>>>(Y, trans, y0, lens, (float*)d_out);
}